// Round 5
// baseline (149.839 us; speedup 1.0000x reference)
//
#include <hip/hip_runtime.h>
#include <hip/hip_bf16.h>

#define G      4000
#define DEG    32
#define BATCH  128
#define D      32000          // G*8
#define NBLK   132000         // G*DEG + G
#define ZBLK   NBLK           // extra all-zero w block for K-padding
#define CAP    96             // per-dest capacity (max degree ~62 for seed 0, Poisson(33))

typedef __attribute__((ext_vector_type(8))) short bf16x8;
typedef __attribute__((ext_vector_type(4))) float f32x4;

__device__ inline unsigned bf16rne(float f) {
    unsigned u = __float_as_uint(f);
    return (u + 0x7fffu + ((u >> 16) & 1u)) >> 16;
}

__global__ void zero_cnt_kernel(int* cnt) {
    int i = blockIdx.x * 256 + threadIdx.x;
    if (i < G) cnt[i] = 0;
}

// ---------------- fused prep: CSR build | x->bf16 transpose | w->bf16 block-transpose ----------------
#define NB_BUILD 516                       // ceil(132000/256)
#define NB_TR    1000                      // 250 col-tiles x 4 row-tiles (32 batch x 128 col)
#define NB_W     2063                      // ceil((NBLK+1)/64), 64 w-blocks per workgroup

__global__ __launch_bounds__(256) void prep_kernel(const float* __restrict__ x,
                                                   const float* __restrict__ w,
                                                   const int* __restrict__ block_in,
                                                   const int* __restrict__ block_out,
                                                   int* __restrict__ cnt,
                                                   int2* __restrict__ pairs,
                                                   unsigned short* __restrict__ xgb,
                                                   unsigned short* __restrict__ wtb) {
    __shared__ float shmem[64 * 68];       // w-branch: 64 blocks, row-pad 68 (bank-spread)
                                           // x-branch: 32 x 132 tile (4224 <= 4352)
    const int bid = blockIdx.x;
    const int t   = threadIdx.x;

    if (bid < NB_BUILD) {
        // ---- build (n, src) buckets per destination group ----
        int n = bid * 256 + t;
        if (n < NBLK) {
            int dst = block_out[n];
            int src = block_in[n];
            int pos = atomicAdd(&cnt[dst], 1);
            if (pos < CAP) pairs[dst * CAP + pos] = make_int2(n, src);
        }
    } else if (bid < NB_BUILD + NB_TR) {
        // ---- transpose x (BATCH, D) -> xgb bf16 (G, BATCH, 8) ----
        int id = bid - NB_BUILD;
        int c0 = (id % 250) * 128;
        int b0 = (id / 250) * 32;
#pragma unroll
        for (int it = 0; it < 4; ++it) {
            int l  = it * 1024 + t * 4;
            int br = l >> 7;
            int c  = l & 127;
            float4 v = *(const float4*)(x + (size_t)(b0 + br) * D + c0 + c);
            *(float4*)&shmem[br * 132 + c] = v;
        }
        __syncthreads();
#pragma unroll
        for (int it = 0; it < 2; ++it) {
            int idx = it * 256 + t;
            int gl  = idx >> 5;
            int bl  = idx & 31;
            float4 v0 = *(const float4*)&shmem[bl * 132 + gl * 8];
            float4 v1 = *(const float4*)&shmem[bl * 132 + gl * 8 + 4];
            uint4 p;
            p.x = bf16rne(v0.x) | (bf16rne(v0.y) << 16);
            p.y = bf16rne(v0.z) | (bf16rne(v0.w) << 16);
            p.z = bf16rne(v1.x) | (bf16rne(v1.y) << 16);
            p.w = bf16rne(v1.z) | (bf16rne(v1.w) << 16);
            int gidx = (c0 >> 3) + gl;
            *(uint4*)(xgb + ((size_t)gidx * BATCH + b0 + bl) * 8) = p;
        }
    } else {
        // ---- wtb[n][o][i] = bf16(w[n][i][o]); block ZBLK = zeros ----
        // 64 w-blocks per workgroup. Coalesced float4 global loads -> padded LDS
        // -> per-(n,o) pack -> coalesced uint4 stores.
        int    id       = bid - (NB_BUILD + NB_TR);
        size_t base_blk = (size_t)id * 64;
        const float* wb = w + base_blk * 64;
#pragma unroll
        for (int j = 0; j < 4; ++j) {
            int pos  = j * 1024 + t * 4;           // flat element 0..4095
            int nl   = pos >> 6;
            int rest = pos & 63;
            float4 v;
            if (base_blk + nl < NBLK) v = *(const float4*)(wb + pos);
            else                      v = make_float4(0.f, 0.f, 0.f, 0.f);
            *(float4*)&shmem[nl * 68 + rest] = v;
        }
        __syncthreads();
#pragma unroll
        for (int j = 0; j < 2; ++j) {
            int p  = j * 256 + t;                  // 0..511 = 64 blocks x 8 o
            int nl = p >> 3;
            int o  = p & 7;
            size_t nglob = base_blk + nl;
            if (nglob <= NBLK) {
                const float* r = &shmem[nl * 68 + o];
                uint4 q;
                q.x = bf16rne(r[0])  | (bf16rne(r[8])  << 16);
                q.y = bf16rne(r[16]) | (bf16rne(r[24]) << 16);
                q.z = bf16rne(r[32]) | (bf16rne(r[40]) << 16);
                q.w = bf16rne(r[48]) | (bf16rne(r[56]) << 16);
                *(uint4*)(wtb + nglob * 64 + o * 8) = q;
            }
        }
    }
}

// ---------------- main compute: MFMA per group, depth-4 pipeline ----------------
// Block = 1 group, 4 waves. Wave covers m-tiles (wave*2, wave*2+1) of batch.
// K-step = 4 edges (quad = edge). Tail steps padded with ZBLK (zero w).
__global__ __launch_bounds__(256) void compute_kernel(const float* __restrict__ x,
                                                      const unsigned short* __restrict__ xgb,
                                                      const unsigned short* __restrict__ wtb,
                                                      const int2* __restrict__ pairs,
                                                      const int* __restrict__ cnt,
                                                      float* __restrict__ out) {
    const int g    = blockIdx.x;
    const int t    = threadIdx.x;
    const int wave = t >> 6;
    const int lane = t & 63;
    const int quad = lane >> 4;
    const int lo16 = lane & 15;

    __shared__ int sn[CAP];
    __shared__ int ss[CAP];

    int m = cnt[g];
    if (m > CAP) m = CAP;
    if (t < m) {
        int2 e = pairs[(size_t)g * CAP + t];
        sn[t] = e.x;
        ss[t] = e.y;
    }
    __syncthreads();

    const int    ob8   = (lo16 & 7) * 8;        // element offset into wtb block
    const int    mt0   = wave * 32 + lo16;      // batch row, tile 0
    const size_t a0off = (size_t)mt0 * 8;       // element offset into xgb block
    const size_t a1off = a0off + 128;           // +16 rows

    f32x4 acc0 = {0.f, 0.f, 0.f, 0.f};
    f32x4 acc1 = {0.f, 0.f, 0.f, 0.f};

#define LOADSTEP(k0, A0, A1, BB)                                          \
    do {                                                                  \
        int kq_ = (k0) + quad;                                            \
        int v_  = kq_ < m;                                                \
        int kc_ = v_ ? kq_ : 0;                                           \
        int n_  = v_ ? sn[kc_] : ZBLK;                                    \
        int s_  = v_ ? ss[kc_] : 0;                                       \
        BB = *(const uint4*)(wtb + ((size_t)n_ << 6) + ob8);              \
        A0 = *(const uint4*)(xgb + ((size_t)s_ << 10) + a0off);           \
        A1 = *(const uint4*)(xgb + ((size_t)s_ << 10) + a1off);           \
    } while (0)

#define CONS(A0, A1, BB)                                                  \
    do {                                                                  \
        acc0 = __builtin_amdgcn_mfma_f32_16x16x32_bf16(                   \
            __builtin_bit_cast(bf16x8, A0), __builtin_bit_cast(bf16x8, BB), acc0, 0, 0, 0); \
        acc1 = __builtin_amdgcn_mfma_f32_16x16x32_bf16(                   \
            __builtin_bit_cast(bf16x8, A1), __builtin_bit_cast(bf16x8, BB), acc1, 0, 0, 0); \
    } while (0)

    uint4 Pa0, Pa1, Pb;    // pipeline buffers, steps k0+0
    uint4 Qa0, Qa1, Qb;    //                   steps k0+4
    uint4 Ra0, Ra1, Rb;    //                   steps k0+8
    uint4 Sa0, Sa1, Sb;    //                   steps k0+12

    LOADSTEP(0,  Pa0, Pa1, Pb);
    LOADSTEP(4,  Qa0, Qa1, Qb);
    LOADSTEP(8,  Ra0, Ra1, Rb);
    LOADSTEP(12, Sa0, Sa1, Sb);

    for (int k0 = 0; k0 < m; k0 += 16) {
        CONS(Pa0, Pa1, Pb);
        LOADSTEP(k0 + 16, Pa0, Pa1, Pb);
        CONS(Qa0, Qa1, Qb);
        LOADSTEP(k0 + 20, Qa0, Qa1, Qb);
        CONS(Ra0, Ra1, Rb);
        LOADSTEP(k0 + 24, Ra0, Ra1, Rb);
        CONS(Sa0, Sa1, Sb);
        LOADSTEP(k0 + 28, Sa0, Sa1, Sb);
    }

    // epilogue: C[row][col] (col=lane&15, row=quad*4+r per tile) + residual from x
    if (lo16 < 8) {
        const int col = g * 8 + lo16;
#pragma unroll
        for (int r = 0; r < 4; ++r) {
            int row0 = wave * 32 + quad * 4 + r;
            int row1 = row0 + 16;
            out[(size_t)row0 * D + col] = acc0[r] + x[(size_t)row0 * D + col];
            out[(size_t)row1 * D + col] = acc1[r] + x[(size_t)row1 * D + col];
        }
    }
#undef LOADSTEP
#undef CONS
}

extern "C" void kernel_launch(void* const* d_in, const int* in_sizes, int n_in,
                              void* d_out, int out_size, void* d_ws, size_t ws_size,
                              hipStream_t stream) {
    const float* x         = (const float*)d_in[0];
    const float* w         = (const float*)d_in[1];
    const int*   block_in  = (const int*)d_in[2];
    const int*   block_out = (const int*)d_in[3];
    float*       out       = (float*)d_out;

    // workspace layout (total 28,176,512 B)
    char* ws = (char*)d_ws;
    int*            cnt   = (int*)ws;                                   // 16,384 B
    int2*           pairs = (int2*)(ws + 16384);                        // 3,072,000 B
    unsigned short* xgb   = (unsigned short*)(ws + 3088384);            // 8,192,000 B
    unsigned short* wtb   = (unsigned short*)(ws + 11280384);           // 16,896,128 B

    zero_cnt_kernel<<<16, 256, 0, stream>>>(cnt);
    prep_kernel<<<NB_BUILD + NB_TR + NB_W, 256, 0, stream>>>(x, w, block_in, block_out,
                                                             cnt, pairs, xgb, wtb);
    compute_kernel<<<G, 256, 0, stream>>>(x, xgb, wtb, pairs, cnt, out);
}

// Round 6
// 149.397 us; speedup vs baseline: 1.0030x; 1.0030x over previous
//
#include <hip/hip_runtime.h>
#include <hip/hip_bf16.h>

#define G      4000
#define DEG    32
#define BATCH  128
#define D      32000          // G*8
#define NBLK   132000         // G*DEG + G
#define ZBLK   NBLK           // extra all-zero w block for K-padding
#define CAP    96             // per-dest capacity (max degree ~62 for seed 0, Poisson(33))
#define SCAP   128            // padded LDS edge-list size (covers k0+28+quad overrun)

typedef __attribute__((ext_vector_type(8))) short bf16x8;
typedef __attribute__((ext_vector_type(4))) float f32x4;

__device__ inline unsigned bf16rne(float f) {
    unsigned u = __float_as_uint(f);
    return (u + 0x7fffu + ((u >> 16) & 1u)) >> 16;
}

__global__ void zero_cnt_kernel(int* cnt) {
    int i = blockIdx.x * 256 + threadIdx.x;
    if (i < G) cnt[i] = 0;
}

// ---------------- fused prep: CSR build | x->bf16 transpose | w->bf16 block-transpose ----------------
#define NB_BUILD 516                       // ceil(132000/256)
#define NB_TR    1000                      // 250 col-tiles x 4 row-tiles (32 batch x 128 col)
#define NB_W     2063                      // ceil((NBLK+1)/64), 64 w-blocks per workgroup

__global__ __launch_bounds__(256) void prep_kernel(const float* __restrict__ x,
                                                   const float* __restrict__ w,
                                                   const int* __restrict__ block_in,
                                                   const int* __restrict__ block_out,
                                                   int* __restrict__ cnt,
                                                   int2* __restrict__ pairs,
                                                   unsigned short* __restrict__ xgb,
                                                   unsigned short* __restrict__ wtb) {
    __shared__ float shmem[64 * 68];       // w-branch: 64 blocks, row-pad 68 (bank-spread)
                                           // x-branch: 32 x 132 tile (4224 <= 4352)
    const int bid = blockIdx.x;
    const int t   = threadIdx.x;

    if (bid < NB_BUILD) {
        // ---- build (n, src) buckets per destination group ----
        int n = bid * 256 + t;
        if (n < NBLK) {
            int dst = block_out[n];
            int src = block_in[n];
            int pos = atomicAdd(&cnt[dst], 1);
            if (pos < CAP) pairs[dst * CAP + pos] = make_int2(n, src);
        }
    } else if (bid < NB_BUILD + NB_TR) {
        // ---- transpose x (BATCH, D) -> xgb bf16 (G, BATCH, 8) ----
        int id = bid - NB_BUILD;
        int c0 = (id % 250) * 128;
        int b0 = (id / 250) * 32;
#pragma unroll
        for (int it = 0; it < 4; ++it) {
            int l  = it * 1024 + t * 4;
            int br = l >> 7;
            int c  = l & 127;
            float4 v = *(const float4*)(x + (size_t)(b0 + br) * D + c0 + c);
            *(float4*)&shmem[br * 132 + c] = v;
        }
        __syncthreads();
#pragma unroll
        for (int it = 0; it < 2; ++it) {
            int idx = it * 256 + t;
            int gl  = idx >> 5;
            int bl  = idx & 31;
            float4 v0 = *(const float4*)&shmem[bl * 132 + gl * 8];
            float4 v1 = *(const float4*)&shmem[bl * 132 + gl * 8 + 4];
            uint4 p;
            p.x = bf16rne(v0.x) | (bf16rne(v0.y) << 16);
            p.y = bf16rne(v0.z) | (bf16rne(v0.w) << 16);
            p.z = bf16rne(v1.x) | (bf16rne(v1.y) << 16);
            p.w = bf16rne(v1.z) | (bf16rne(v1.w) << 16);
            int gidx = (c0 >> 3) + gl;
            *(uint4*)(xgb + ((size_t)gidx * BATCH + b0 + bl) * 8) = p;
        }
    } else {
        // ---- wtb[n][o][i] = bf16(w[n][i][o]); block ZBLK = zeros ----
        int    id       = bid - (NB_BUILD + NB_TR);
        size_t base_blk = (size_t)id * 64;
        const float* wb = w + base_blk * 64;
#pragma unroll
        for (int j = 0; j < 4; ++j) {
            int pos  = j * 1024 + t * 4;           // flat element 0..4095
            int nl   = pos >> 6;
            int rest = pos & 63;
            float4 v;
            if (base_blk + nl < NBLK) v = *(const float4*)(wb + pos);
            else                      v = make_float4(0.f, 0.f, 0.f, 0.f);
            *(float4*)&shmem[nl * 68 + rest] = v;
        }
        __syncthreads();
#pragma unroll
        for (int j = 0; j < 2; ++j) {
            int p  = j * 256 + t;                  // 0..511 = 64 blocks x 8 o
            int nl = p >> 3;
            int o  = p & 7;
            size_t nglob = base_blk + nl;
            if (nglob <= NBLK) {
                const float* r = &shmem[nl * 68 + o];
                uint4 q;
                q.x = bf16rne(r[0])  | (bf16rne(r[8])  << 16);
                q.y = bf16rne(r[16]) | (bf16rne(r[24]) << 16);
                q.z = bf16rne(r[32]) | (bf16rne(r[40]) << 16);
                q.w = bf16rne(r[48]) | (bf16rne(r[56]) << 16);
                *(uint4*)(wtb + nglob * 64 + o * 8) = q;
            }
        }
    }
}

// ---------------- main compute: MFMA per group, depth-4 FORCED pipeline ----------------
// Block = 1 group, 4 waves. Wave covers m-tiles (wave*2, wave*2+1) of batch.
// K-step = 4 edges (quad = edge). Edge list ZBLK-padded in LDS -> branchless steps.
// sched_barrier(0) after each LOADSTEP keeps ~12 gathers in flight (compiler
// collapsed the R4/R5 pipelines to depth-1: VGPR_Count was 28/36).
__global__ __launch_bounds__(256) void compute_kernel(const float* __restrict__ x,
                                                      const unsigned short* __restrict__ xgb,
                                                      const unsigned short* __restrict__ wtb,
                                                      const int2* __restrict__ pairs,
                                                      const int* __restrict__ cnt,
                                                      float* __restrict__ out) {
    const int g    = blockIdx.x;
    const int t    = threadIdx.x;
    const int wave = t >> 6;
    const int lane = t & 63;
    const int quad = lane >> 4;
    const int lo16 = lane & 15;

    __shared__ int2 se[SCAP];

    int m = cnt[g];
    if (m > CAP) m = CAP;
    if (t < SCAP) {
        int2 e = (t < m) ? pairs[(size_t)g * CAP + t] : make_int2(ZBLK, 0);
        se[t] = e;
    }
    __syncthreads();

    const int ob8   = (lo16 & 7) * 8;        // element offset into wtb block
    const int mt0   = wave * 32 + lo16;      // batch row, tile 0
    const int a0off = mt0 * 8;               // element offset into xgb block
    const int a1off = a0off + 128;           // +16 rows

    f32x4 acc0 = {0.f, 0.f, 0.f, 0.f};
    f32x4 acc1 = {0.f, 0.f, 0.f, 0.f};

#define LOADSTEP(k0, A0, A1, BB)                                          \
    do {                                                                  \
        int2 e_ = se[(k0) + quad];                                        \
        BB = *(const uint4*)(wtb + ((size_t)e_.x << 6) + ob8);            \
        A0 = *(const uint4*)(xgb + ((size_t)e_.y << 10) + a0off);         \
        A1 = *(const uint4*)(xgb + ((size_t)e_.y << 10) + a1off);         \
    } while (0)

#define CONS(A0, A1, BB)                                                  \
    do {                                                                  \
        acc0 = __builtin_amdgcn_mfma_f32_16x16x32_bf16(                   \
            __builtin_bit_cast(bf16x8, A0), __builtin_bit_cast(bf16x8, BB), acc0, 0, 0, 0); \
        acc1 = __builtin_amdgcn_mfma_f32_16x16x32_bf16(                   \
            __builtin_bit_cast(bf16x8, A1), __builtin_bit_cast(bf16x8, BB), acc1, 0, 0, 0); \
    } while (0)

    uint4 Pa0, Pa1, Pb;    // pipeline buffers, steps k0+0
    uint4 Qa0, Qa1, Qb;    //                   steps k0+4
    uint4 Ra0, Ra1, Rb;    //                   steps k0+8
    uint4 Sa0, Sa1, Sb;    //                   steps k0+12

    LOADSTEP(0,  Pa0, Pa1, Pb);
    LOADSTEP(4,  Qa0, Qa1, Qb);
    LOADSTEP(8,  Ra0, Ra1, Rb);
    LOADSTEP(12, Sa0, Sa1, Sb);
    __builtin_amdgcn_sched_barrier(0);

    for (int k0 = 0; k0 < m; k0 += 16) {
        CONS(Pa0, Pa1, Pb);
        LOADSTEP(k0 + 16, Pa0, Pa1, Pb);
        __builtin_amdgcn_sched_barrier(0);
        CONS(Qa0, Qa1, Qb);
        LOADSTEP(k0 + 20, Qa0, Qa1, Qb);
        __builtin_amdgcn_sched_barrier(0);
        CONS(Ra0, Ra1, Rb);
        LOADSTEP(k0 + 24, Ra0, Ra1, Rb);
        __builtin_amdgcn_sched_barrier(0);
        CONS(Sa0, Sa1, Sb);
        LOADSTEP(k0 + 28, Sa0, Sa1, Sb);
        __builtin_amdgcn_sched_barrier(0);
    }

    // epilogue: C[row][col] (col=lane&15, row=quad*4+r per tile) + residual from x
    if (lo16 < 8) {
        const int col = g * 8 + lo16;
#pragma unroll
        for (int r = 0; r < 4; ++r) {
            int row0 = wave * 32 + quad * 4 + r;
            int row1 = row0 + 16;
            out[(size_t)row0 * D + col] = acc0[r] + x[(size_t)row0 * D + col];
            out[(size_t)row1 * D + col] = acc1[r] + x[(size_t)row1 * D + col];
        }
    }
#undef LOADSTEP
#undef CONS
}

extern "C" void kernel_launch(void* const* d_in, const int* in_sizes, int n_in,
                              void* d_out, int out_size, void* d_ws, size_t ws_size,
                              hipStream_t stream) {
    const float* x         = (const float*)d_in[0];
    const float* w         = (const float*)d_in[1];
    const int*   block_in  = (const int*)d_in[2];
    const int*   block_out = (const int*)d_in[3];
    float*       out       = (float*)d_out;

    // workspace layout (total 28,176,512 B)
    char* ws = (char*)d_ws;
    int*            cnt   = (int*)ws;                                   // 16,384 B
    int2*           pairs = (int2*)(ws + 16384);                        // 3,072,000 B
    unsigned short* xgb   = (unsigned short*)(ws + 3088384);            // 8,192,000 B
    unsigned short* wtb   = (unsigned short*)(ws + 11280384);           // 16,896,128 B

    zero_cnt_kernel<<<16, 256, 0, stream>>>(cnt);
    prep_kernel<<<NB_BUILD + NB_TR + NB_W, 256, 0, stream>>>(x, w, block_in, block_out,
                                                             cnt, pairs, xgb, wtb);
    compute_kernel<<<G, 256, 0, stream>>>(x, xgb, wtb, pairs, cnt, out);
}

// Round 7
// 141.740 us; speedup vs baseline: 1.0571x; 1.0540x over previous
//
#include <hip/hip_runtime.h>
#include <hip/hip_bf16.h>

#define G      4000
#define DEG    32
#define BATCH  128
#define D      32000          // G*8
#define NBLK   132000         // G*DEG + G
#define ZBLK   NBLK           // extra all-zero w block for K-padding
#define CAP    96             // per-dest capacity (max degree ~62 for seed 0, Poisson(33))
#define SCAP   112            // padded edge count (covers k0+28+quad overrun at m=96)

typedef __attribute__((ext_vector_type(8))) short bf16x8;
typedef __attribute__((ext_vector_type(4))) float f32x4;

__device__ inline unsigned bf16rne(float f) {
    unsigned u = __float_as_uint(f);
    return (u + 0x7fffu + ((u >> 16) & 1u)) >> 16;
}

__global__ void zero_cnt_kernel(int* cnt) {
    int i = blockIdx.x * 256 + threadIdx.x;
    if (i < G) cnt[i] = 0;
}

// ---------------- fused prep: CSR build | x->bf16 transpose | w->bf16 block-transpose ----------------
#define NB_BUILD 516                       // ceil(132000/256)
#define NB_TR    1000                      // 250 col-tiles x 4 row-tiles (32 batch x 128 col)
#define NB_W     2063                      // ceil((NBLK+1)/64), 64 w-blocks per workgroup

__global__ __launch_bounds__(256) void prep_kernel(const float* __restrict__ x,
                                                   const float* __restrict__ w,
                                                   const int* __restrict__ block_in,
                                                   const int* __restrict__ block_out,
                                                   int* __restrict__ cnt,
                                                   int2* __restrict__ pairs,
                                                   unsigned short* __restrict__ xgb,
                                                   unsigned short* __restrict__ wtb) {
    __shared__ float shmem[64 * 68];       // w-branch: 64 blocks, row-pad 68 (bank-spread)
                                           // x-branch: 32 x 132 tile (4224 <= 4352)
    const int bid = blockIdx.x;
    const int t   = threadIdx.x;

    if (bid < NB_BUILD) {
        // ---- build (n, src) buckets per destination group ----
        int n = bid * 256 + t;
        if (n < NBLK) {
            int dst = block_out[n];
            int src = block_in[n];
            int pos = atomicAdd(&cnt[dst], 1);
            if (pos < CAP) pairs[dst * CAP + pos] = make_int2(n, src);
        }
    } else if (bid < NB_BUILD + NB_TR) {
        // ---- transpose x (BATCH, D) -> xgb bf16 [half][g][64][8] (half = batch/64) ----
        int id = bid - NB_BUILD;
        int c0 = (id % 250) * 128;
        int b0 = (id / 250) * 32;          // batch row base: 0,32,64,96
        int half = (b0 >= 64) ? 1 : 0;
        int lr0  = b0 & 63;                // local row base within half
#pragma unroll
        for (int it = 0; it < 4; ++it) {
            int l  = it * 1024 + t * 4;
            int br = l >> 7;
            int c  = l & 127;
            float4 v = *(const float4*)(x + (size_t)(b0 + br) * D + c0 + c);
            *(float4*)&shmem[br * 132 + c] = v;
        }
        __syncthreads();
#pragma unroll
        for (int it = 0; it < 2; ++it) {
            int idx = it * 256 + t;
            int gl  = idx >> 5;
            int bl  = idx & 31;
            float4 v0 = *(const float4*)&shmem[bl * 132 + gl * 8];
            float4 v1 = *(const float4*)&shmem[bl * 132 + gl * 8 + 4];
            uint4 p;
            p.x = bf16rne(v0.x) | (bf16rne(v0.y) << 16);
            p.y = bf16rne(v0.z) | (bf16rne(v0.w) << 16);
            p.z = bf16rne(v1.x) | (bf16rne(v1.y) << 16);
            p.w = bf16rne(v1.z) | (bf16rne(v1.w) << 16);
            int gidx = (c0 >> 3) + gl;
            size_t base = (((size_t)half * G + gidx) * 64 + lr0 + bl) * 8;
            *(uint4*)(xgb + base) = p;
        }
    } else {
        // ---- wtb[n][o][i] = bf16(w[n][i][o]); block ZBLK = zeros ----
        int    id       = bid - (NB_BUILD + NB_TR);
        size_t base_blk = (size_t)id * 64;
        const float* wb = w + base_blk * 64;
#pragma unroll
        for (int j = 0; j < 4; ++j) {
            int pos  = j * 1024 + t * 4;           // flat element 0..4095
            int nl   = pos >> 6;
            int rest = pos & 63;
            float4 v;
            if (base_blk + nl < NBLK) v = *(const float4*)(wb + pos);
            else                      v = make_float4(0.f, 0.f, 0.f, 0.f);
            *(float4*)&shmem[nl * 68 + rest] = v;
        }
        __syncthreads();
#pragma unroll
        for (int j = 0; j < 2; ++j) {
            int p  = j * 256 + t;                  // 0..511 = 64 blocks x 8 o
            int nl = p >> 3;
            int o  = p & 7;
            size_t nglob = base_blk + nl;
            if (nglob <= NBLK) {
                const float* r = &shmem[nl * 68 + o];
                uint4 q;
                q.x = bf16rne(r[0])  | (bf16rne(r[8])  << 16);
                q.y = bf16rne(r[16]) | (bf16rne(r[24]) << 16);
                q.z = bf16rne(r[32]) | (bf16rne(r[40]) << 16);
                q.w = bf16rne(r[48]) | (bf16rne(r[56]) << 16);
                *(uint4*)(wtb + nglob * 64 + o * 8) = q;
            }
        }
    }
}

// ---------------- main compute: MFMA per (group, batch-half) ----------------
// Block = 128 threads (2 waves), covers 64 batch rows of one group.
// half derived from blockIdx&7 so XCDs 0-3 touch only xgb half 0 (4 MB -> L2
// resident), XCDs 4-7 half 1 (blockIdx%8 == XCD heuristic; perf-only).
// All w for the group's edges staged to LDS up front -> in-loop B is ds_read;
// only A-gathers remain global (depth-4 named-register pipeline).
__global__ __launch_bounds__(128) void compute_kernel(const float* __restrict__ x,
                                                      const unsigned short* __restrict__ xgb,
                                                      const unsigned short* __restrict__ wtb,
                                                      const int2* __restrict__ pairs,
                                                      const int* __restrict__ cnt,
                                                      float* __restrict__ out) {
    const int blk  = blockIdx.x;
    const int xcd8 = blk & 7;
    const int half = xcd8 >> 2;
    const int g    = (blk >> 3) * 4 + (blk & 3);
    const int t    = threadIdx.x;
    const int wave = t >> 6;                 // 0/1
    const int lane = t & 63;
    const int quad = lane >> 4;
    const int lo16 = lane & 15;

    __shared__ int2  se[SCAP];
    __shared__ uint4 wl[SCAP * 8];           // 112 edges x 128 B of wtb

    int m = cnt[g];
    if (m > CAP) m = CAP;
    if (t < SCAP) {
        int2 e = (t < m) ? pairs[(size_t)g * CAP + t] : make_int2(ZBLK, 0);
        se[t] = e;
    }
    __syncthreads();

    // stage w: 112 edges x 8 uint4 = 896 uint4, 128 threads -> 7 rounds
#pragma unroll
    for (int r = 0; r < 7; ++r) {
        int idx = r * 128 + t;
        int e   = idx >> 3;
        int j   = idx & 7;
        int n   = se[e].x;
        wl[idx] = *(const uint4*)(wtb + ((size_t)n << 6) + j * 8);
    }
    __syncthreads();

    const int ob   = lo16 & 7;               // uint4 index within edge's w row
    const int mt0  = wave * 32 + lo16;       // local batch row, tile 0 (0..47)
    const int a0off = mt0 * 8;               // element offset into 64-row x-block
    const int a1off = a0off + 128;           // +16 rows
    const size_t hbase = (size_t)half * G;   // block index base for this half

    f32x4 acc0 = {0.f, 0.f, 0.f, 0.f};
    f32x4 acc1 = {0.f, 0.f, 0.f, 0.f};

#define LOADA(k0, A0, A1)                                                 \
    do {                                                                  \
        int s_ = se[(k0) + quad].y;                                       \
        const unsigned short* xb_ = xgb + ((hbase + s_) << 9);            \
        A0 = *(const uint4*)(xb_ + a0off);                                \
        A1 = *(const uint4*)(xb_ + a1off);                                \
    } while (0)

#define CONS(k0, A0, A1)                                                  \
    do {                                                                  \
        uint4 BB = wl[((k0) + quad) * 8 + ob];                            \
        acc0 = __builtin_amdgcn_mfma_f32_16x16x32_bf16(                   \
            __builtin_bit_cast(bf16x8, A0), __builtin_bit_cast(bf16x8, BB), acc0, 0, 0, 0); \
        acc1 = __builtin_amdgcn_mfma_f32_16x16x32_bf16(                   \
            __builtin_bit_cast(bf16x8, A1), __builtin_bit_cast(bf16x8, BB), acc1, 0, 0, 0); \
    } while (0)

    uint4 Pa0, Pa1, Qa0, Qa1, Ra0, Ra1, Sa0, Sa1;

    LOADA(0,  Pa0, Pa1);
    LOADA(4,  Qa0, Qa1);
    LOADA(8,  Ra0, Ra1);
    LOADA(12, Sa0, Sa1);

    for (int k0 = 0; k0 < m; k0 += 16) {
        CONS(k0, Pa0, Pa1);
        LOADA(k0 + 16, Pa0, Pa1);
        CONS(k0 + 4, Qa0, Qa1);
        LOADA(k0 + 20, Qa0, Qa1);
        CONS(k0 + 8, Ra0, Ra1);
        LOADA(k0 + 24, Ra0, Ra1);
        CONS(k0 + 12, Sa0, Sa1);
        LOADA(k0 + 28, Sa0, Sa1);
    }

    // epilogue: C[row][col] (col=lane&15, row=quad*4+r per tile) + residual from x
    if (lo16 < 8) {
        const int col = g * 8 + lo16;
#pragma unroll
        for (int r = 0; r < 4; ++r) {
            int row0 = half * 64 + wave * 32 + quad * 4 + r;
            int row1 = row0 + 16;
            out[(size_t)row0 * D + col] = acc0[r] + x[(size_t)row0 * D + col];
            out[(size_t)row1 * D + col] = acc1[r] + x[(size_t)row1 * D + col];
        }
    }
#undef LOADA
#undef CONS
}

extern "C" void kernel_launch(void* const* d_in, const int* in_sizes, int n_in,
                              void* d_out, int out_size, void* d_ws, size_t ws_size,
                              hipStream_t stream) {
    const float* x         = (const float*)d_in[0];
    const float* w         = (const float*)d_in[1];
    const int*   block_in  = (const int*)d_in[2];
    const int*   block_out = (const int*)d_in[3];
    float*       out       = (float*)d_out;

    // workspace layout (total 28,176,512 B)
    char* ws = (char*)d_ws;
    int*            cnt   = (int*)ws;                                   // 16,384 B
    int2*           pairs = (int2*)(ws + 16384);                        // 3,072,000 B
    unsigned short* xgb   = (unsigned short*)(ws + 3088384);            // 8,192,000 B
    unsigned short* wtb   = (unsigned short*)(ws + 11280384);           // 16,896,128 B

    zero_cnt_kernel<<<16, 256, 0, stream>>>(cnt);
    prep_kernel<<<NB_BUILD + NB_TR + NB_W, 256, 0, stream>>>(x, w, block_in, block_out,
                                                             cnt, pairs, xgb, wtb);
    compute_kernel<<<G * 2, 128, 0, stream>>>(x, xgb, wtb, pairs, cnt, out);
}